// Round 9
// baseline (162.218 us; speedup 1.0000x reference)
//
#include <hip/hip_runtime.h>
#include <hip/hip_bf16.h>

#define NHEADS 32
#define HD_ 32
#define TSEQ 2048
#define SCALE_ 0.12f
#define LOG2E_ 1.44269504088896f
#define RMS_EPS_ 1.1920929e-07f

typedef unsigned short ushort_t;
typedef __bf16 bf16_t;
typedef __attribute__((ext_vector_type(8))) bf16_t bf16x8;
typedef __attribute__((ext_vector_type(4))) float f32x4;
typedef __attribute__((ext_vector_type(8))) unsigned short u16x8;

__device__ __forceinline__ ushort_t f2bfn(float f){
    __hip_bfloat16 b = __float2bfloat16(f);
    return *reinterpret_cast<ushort_t*>(&b);
}
__device__ __forceinline__ float fexp2(float x){
#if __has_builtin(__builtin_amdgcn_exp2f)
    return __builtin_amdgcn_exp2f(x);
#else
    return exp2f(x);
#endif
}
__device__ __forceinline__ void gld16(const void* g, void* l){
    __builtin_amdgcn_global_load_lds(
        (const __attribute__((address_space(1))) unsigned int*)g,
        (__attribute__((address_space(3))) unsigned int*)l,
        16, 0, 0);
}
__device__ __forceinline__ u16x8 pack8(float4 a, float4 b){
    u16x8 o;
    o[0]=f2bfn(a.x); o[1]=f2bfn(a.y); o[2]=f2bfn(a.z); o[3]=f2bfn(a.w);
    o[4]=f2bfn(b.x); o[5]=f2bfn(b.y); o[6]=f2bfn(b.z); o[7]=f2bfn(b.w);
    return o;
}

// ---------------- QKV GEMM (fp32 inputs reg-staged) + fused epilogue ----------------
// BM=128, BN=64, BK=32, dbuf. grid 768 flat: xcd=bid&7 -> m-bands {2xcd,2xcd+1} (A L2-resident).
// LDS slot-XOR swizzle (key=(row>>1)&3) on both write and read -> 2-way conflicts only.
// Epilogue: q/k RMSNorm + inline rotary (freq = 2^-i exact) + SCALE*LOG2E into q;
//           v lam-mix + LDS transpose -> vtb[h][d][t].
__global__ __launch_bounds__(256, 3) void k_gemm_qkv(const float* __restrict__ X,
                                                     const float* __restrict__ W,
                                                     const float* __restrict__ ve,
                                                     const float* __restrict__ lam,
                                                     ushort_t* __restrict__ qb,
                                                     ushort_t* __restrict__ kbuf,
                                                     ushort_t* __restrict__ vtb)
{
    const int K = 1024;
    __shared__ __align__(16) ushort_t As[2][128 * 32];
    __shared__ __align__(16) ushort_t Bs[2][64 * 32];
    const int tid = threadIdx.x;
    const int lane = tid & 63;
    const int w = tid >> 6;
    const int wr = w >> 1, wc = w & 1;
    const int l15 = lane & 15, hi = lane >> 4;

    const int bid = blockIdx.x;                 // 768 blocks
    const int xcd = bid & 7, j = bid >> 3;      // j 0..95
    const int m0 = (xcd * 2 + (j & 1)) * 128;
    const int nidx = j >> 1;                    // 0..47
    const int n0 = nidx * 64;
    const int sec = nidx >> 4;                  // 0=q 1=k 2=v
    const int h = ((nidx & 15) << 1) + wc;      // head for this wave's quadrant

    // reg staging: A thread = (row, half of 32 cols); B thread = (row, quarter)
    const int arow = tid >> 1, ahalf = tid & 1;
    const int brow = tid >> 2, bq = tid & 3;
    const int akey = (arow >> 1) & 3;
    const int bkey = (brow >> 1) & 3;
    float4 ra[4], rb[2];

    auto loadRegs = [&](int k0){
        const float4* pa = (const float4*)&X[(size_t)(m0 + arow) * K + k0 + ahalf * 16];
        ra[0] = pa[0]; ra[1] = pa[1]; ra[2] = pa[2]; ra[3] = pa[3];
        const float4* pb = (const float4*)&W[(size_t)(n0 + brow) * K + k0 + bq * 8];
        rb[0] = pb[0]; rb[1] = pb[1];
    };
    auto writeLDS = [&](int buf){
        *(u16x8*)&As[buf][arow * 32 + ((ahalf * 2 + 0) ^ akey) * 8] = pack8(ra[0], ra[1]);
        *(u16x8*)&As[buf][arow * 32 + ((ahalf * 2 + 1) ^ akey) * 8] = pack8(ra[2], ra[3]);
        *(u16x8*)&Bs[buf][brow * 32 + (bq ^ bkey) * 8] = pack8(rb[0], rb[1]);
    };

    f32x4 acc[4][2] = {};
    const int kq = (l15 >> 1) & 3;
    const int soff = (hi ^ kq) * 8;

    loadRegs(0);
    int cur = 0;
    for (int k0 = 0; k0 < K; k0 += 32){
        writeLDS(cur);
        __syncthreads();
        if (k0 + 32 < K) loadRegs(k0 + 32);     // overlaps MFMA below
        bf16x8 af[4], bfr[2];
        #pragma unroll
        for (int mi = 0; mi < 4; ++mi)
            af[mi] = *(const bf16x8*)&As[cur][(wr * 64 + mi * 16 + l15) * 32 + soff];
        #pragma unroll
        for (int ni = 0; ni < 2; ++ni)
            bfr[ni] = *(const bf16x8*)&Bs[cur][(wc * 32 + ni * 16 + l15) * 32 + soff];
        #pragma unroll
        for (int mi = 0; mi < 4; ++mi)
            #pragma unroll
            for (int ni = 0; ni < 2; ++ni)
                acc[mi][ni] = __builtin_amdgcn_mfma_f32_16x16x32_bf16(af[mi], bfr[ni], acc[mi][ni], 0, 0, 0);
        cur ^= 1;
    }

    // ---------- fused epilogue ----------
    if (sec < 2){
        ushort_t* dst = (sec == 0) ? qb : kbuf;
        const float qscl = (sec == 0) ? SCALE_ * LOG2E_ : 1.0f;
        const float fs = exp2f(-(float)l15);    // rotary freq 2^-i (exact); i>=8 -> identity
        #pragma unroll
        for (int mi = 0; mi < 4; ++mi){
            #pragma unroll
            for (int r = 0; r < 4; ++r){
                const int t = m0 + wr * 64 + mi * 16 + hi * 4 + r;
                float v0 = acc[mi][0][r], v1 = acc[mi][1][r];
                float ss = v0 * v0 + v1 * v1;
                ss += __shfl_xor(ss, 1);
                ss += __shfl_xor(ss, 2);
                ss += __shfl_xor(ss, 4);
                ss += __shfl_xor(ss, 8);
                const float inv = rsqrtf(ss * (1.0f / 32.0f) + RMS_EPS_);
                float c = 1.0f, s = 0.0f;
                if (l15 < 8) sincosf((float)t * fs, &s, &c);
                const float n0v = v0 * inv, n1v = v1 * inv;
                const float o0 = (n0v * c + n1v * s) * qscl;
                const float o1 = (n1v * c - n0v * s) * qscl;
                size_t base = ((size_t)h * TSEQ + t) * 32;
                dst[base + l15]      = f2bfn(o0);
                dst[base + 16 + l15] = f2bfn(o1);
            }
        }
    } else {
        const float l0 = lam[0], l1 = lam[1];
        __syncthreads();
        ushort_t* vt = &As[0][0] + w * 2048;    // 32 d-rows x 64 t (swizzled 8-col groups)
        #pragma unroll
        for (int ni = 0; ni < 2; ++ni){
            const int d = ni * 16 + l15;
            #pragma unroll
            for (int mi = 0; mi < 4; ++mi){
                #pragma unroll
                for (int r = 0; r < 4; ++r){
                    const int t = m0 + wr * 64 + mi * 16 + hi * 4 + r;
                    const int tl = mi * 16 + hi * 4 + r;
                    float vef = ve[(size_t)t * 1024 + h * 32 + d];
                    float ov = l0 * acc[mi][ni][r] + l1 * vef;
                    const int g = (tl >> 3) ^ (d & 7);
                    vt[d * 64 + g * 8 + (tl & 7)] = f2bfn(ov);
                }
            }
        }
        __syncthreads();
        const int tc = lane & 7;
        #pragma unroll
        for (int p = 0; p < 4; ++p){
            const int d = p * 8 + (lane >> 3);
            const int g = tc ^ (d & 7);
            u16x8 o = *(const u16x8*)&vt[d * 64 + g * 8];
            *(u16x8*)&vtb[((size_t)h * HD_ + d) * TSEQ + m0 + wr * 64 + tc * 8] = o;
        }
    }
}

// ---------------- out-proj GEMM: 64x64, BK=64, dbuf; cpw fp32 reg-staged ----------------
// LDS rows are 128B -> 8 slots; XOR key = row&7 on write/read (and pre-swizzled gld16 source
// for A) turns the former 16-way conflict into 2-way.
__global__ __launch_bounds__(256, 3) void k_gemm_out(const ushort_t* __restrict__ A,
                                                     const float* __restrict__ W2,
                                                     float* __restrict__ C)
{
    const int K = 1024, N = 1024;
    __shared__ __align__(16) ushort_t As2[2][64 * 64];
    __shared__ __align__(16) ushort_t Bs2[2][64 * 64];
    const int tid = threadIdx.x;
    const int lane = tid & 63;
    const int w = tid >> 6;
    const int wr = w >> 1, wc = w & 1;
    const int l15 = lane & 15, hi = lane >> 4;

    const int bid = blockIdx.x;                 // 512 blocks
    const int xcd = bid & 7, j = bid >> 3;      // j 0..63
    const int m0 = (xcd * 4 + (j & 3)) * 64;    // 32 m-bands
    const int n0 = (j >> 2) * 64;               // 16 n-tiles

    const int srow = lane >> 3;                 // A staging: 8 rows/chunk
    const int sslot = (lane & 7) ^ srow;        // pre-swizzled source slot (key=row&7=srow)
    const int brow = tid >> 2, bq = tid & 3;    // B: 64 rows x 4 quarters of 16 floats
    const int bkey = brow & 7;
    float4 rb[4];

    auto stageA = [&](int k0, int buf){
        #pragma unroll
        for (int i = 0; i < 2; ++i){
            int c = w * 2 + i;
            gld16(&A[(size_t)(m0 + c * 8 + srow) * K + k0 + sslot * 8], &As2[buf][c * 512]);
        }
    };
    auto loadB = [&](int k0){
        const float4* p = (const float4*)&W2[(size_t)(n0 + brow) * K + k0 + bq * 16];
        rb[0] = p[0]; rb[1] = p[1]; rb[2] = p[2]; rb[3] = p[3];
    };
    auto writeB = [&](int buf){
        *(u16x8*)&Bs2[buf][brow * 64 + ((bq * 2 + 0) ^ bkey) * 8] = pack8(rb[0], rb[1]);
        *(u16x8*)&Bs2[buf][brow * 64 + ((bq * 2 + 1) ^ bkey) * 8] = pack8(rb[2], rb[3]);
    };

    f32x4 acc[2][2] = {};
    const int rkey = l15 & 7;

    loadB(0);
    stageA(0, 0);
    int cur = 0;
    for (int k0 = 0; k0 < K; k0 += 64){
        writeB(cur);
        __syncthreads();                        // drains gld16 vmcnt + ds writes
        if (k0 + 64 < K){ stageA(k0 + 64, cur ^ 1); loadB(k0 + 64); }
        bf16x8 af[2][2], bfr[2][2];
        #pragma unroll
        for (int mi = 0; mi < 2; ++mi)
            #pragma unroll
            for (int sub = 0; sub < 2; ++sub)
                af[mi][sub] = *(const bf16x8*)&As2[cur][(wr * 32 + mi * 16 + l15) * 64 + ((sub * 4 + hi) ^ rkey) * 8];
        #pragma unroll
        for (int ni = 0; ni < 2; ++ni)
            #pragma unroll
            for (int sub = 0; sub < 2; ++sub)
                bfr[ni][sub] = *(const bf16x8*)&Bs2[cur][(wc * 32 + ni * 16 + l15) * 64 + ((sub * 4 + hi) ^ rkey) * 8];
        #pragma unroll
        for (int sub = 0; sub < 2; ++sub)
            #pragma unroll
            for (int mi = 0; mi < 2; ++mi)
                #pragma unroll
                for (int ni = 0; ni < 2; ++ni)
                    acc[mi][ni] = __builtin_amdgcn_mfma_f32_16x16x32_bf16(af[mi][sub], bfr[ni][sub], acc[mi][ni], 0, 0, 0);
        cur ^= 1;
    }

    #pragma unroll
    for (int mi = 0; mi < 2; ++mi)
        #pragma unroll
        for (int ni = 0; ni < 2; ++ni)
            #pragma unroll
            for (int r = 0; r < 4; ++r){
                int row = m0 + wr * 32 + mi * 16 + hi * 4 + r;
                int col = n0 + wc * 32 + ni * 16 + l15;
                C[(size_t)row * N + col] = acc[mi][ni][r];
            }
}

// ---------------- causal flash attention, 1 q-tile/block, KVBLK=64 dbuf ----------------
// No-max softmax: ||q||=||k||=sqrt(32), SCALE*log2e folded into q -> |s|<=5.6 -> P=exp2(s) raw.
template<bool MASK>
__device__ __forceinline__ void chain_step(const bf16x8* kf, const bf16x8* vv0, const bf16x8* vv1,
                                           ushort_t* pb, const bf16x8& qf,
                                           int kb0, int qrow, int l15, int hi,
                                           f32x4& a0, f32x4& a1, float& lp)
{
    f32x4 s[4];
    __builtin_amdgcn_s_setprio(1);
    #pragma unroll
    for (int ni = 0; ni < 4; ++ni){
        f32x4 z = {0.f, 0.f, 0.f, 0.f};
        s[ni] = __builtin_amdgcn_mfma_f32_16x16x32_bf16(kf[ni], qf, z, 0, 0, 0);  // S^T
    }
    __builtin_amdgcn_s_setprio(0);
    if (MASK){
        const int relc = qrow - kb0 - 4 * hi;
        #pragma unroll
        for (int ni = 0; ni < 4; ++ni)
            #pragma unroll
            for (int r = 0; r < 4; ++r)
                if (16 * ni + r > relc) s[ni][r] = -1e30f;
    }
    float ps = 0.f;
    #pragma unroll
    for (int ni = 0; ni < 4; ++ni)
        #pragma unroll
        for (int r = 0; r < 4; ++r){
            float p = fexp2(s[ni][r]);
            s[ni][r] = p;
            ps += p;
        }
    lp += ps;
    #pragma unroll
    for (int ni = 0; ni < 4; ++ni){
        ushort4 pk;
        pk.x = f2bfn(s[ni][0]); pk.y = f2bfn(s[ni][1]);
        pk.z = f2bfn(s[ni][2]); pk.w = f2bfn(s[ni][3]);
        *(ushort4*)&pb[l15 * 72 + ni * 16 + hi * 4] = pk;
    }
    __builtin_amdgcn_s_setprio(1);
    #pragma unroll
    for (int kk = 0; kk < 2; ++kk){
        bf16x8 pf = *(const bf16x8*)&pb[l15 * 72 + kk * 32 + hi * 8];
        a0 = __builtin_amdgcn_mfma_f32_16x16x32_bf16(vv0[kk], pf, a0, 0, 0, 0);
        a1 = __builtin_amdgcn_mfma_f32_16x16x32_bf16(vv1[kk], pf, a1, 0, 0, 0);
    }
    __builtin_amdgcn_s_setprio(0);
}

// grid 1024 = 8 XCDs x (32 q-tiles x 4 heads), heavy-first. K staged with slot-XOR swizzle
// (pre-swizzled source + swizzled read, key=(row>>1)&3) -> 2-way instead of 8-way conflicts.
__global__ __launch_bounds__(256, 4) void k_attn(const ushort_t* __restrict__ qb,
                                                 const ushort_t* __restrict__ kb,
                                                 const ushort_t* __restrict__ vtb,
                                                 ushort_t* __restrict__ yb)
{
    const int bid = blockIdx.x;
    const int xcd = bid & 7, idx = bid >> 3;
    const int h  = xcd * 4 + (idx & 3);
    const int qt = 31 - (idx >> 2);
    const int tid = threadIdx.x;
    const int w = tid >> 6, lane = tid & 63;
    const int l15 = lane & 15, hi = lane >> 4;

    __shared__ __align__(16) ushort_t Kbuf[2][64 * 32];
    __shared__ __align__(16) ushort_t Vbuf[2][32 * 64];
    __shared__ __align__(16) ushort_t Pbuf[4][16 * 72];

    const ushort_t* kb_h = kb + (size_t)h * TSEQ * HD_;
    const ushort_t* vt_h = vtb + (size_t)h * HD_ * TSEQ;
    const ushort_t* qb_h = qb + (size_t)h * TSEQ * HD_;

    const int qw = qt * 64 + w * 16;
    const bf16x8 qf = *(const bf16x8*)&qb_h[(size_t)(qw + l15) * 32 + hi * 8];

    // staging: K rows 16w.. with pre-swizzled source slot (key=(row>>1)&3 = (lane>>3)&3)
    const int krow = w * 16 + (lane >> 2);
    const int kslot = (lane & 3) ^ ((lane >> 3) & 3);
    const int vrow = w * 8 + (lane >> 3);
    const int vslot = (lane & 7) ^ (vrow & 7);
    auto stage = [&](int kt, int buf){
        const int kb0 = kt * 64;
        gld16(&kb_h[(size_t)(kb0 + krow) * 32 + kslot * 8], &Kbuf[buf][w * 512]);
        gld16(&vt_h[(size_t)vrow * TSEQ + kb0 + vslot * 8], &Vbuf[buf][w * 512]);
    };

    f32x4 a0 = {0.f,0.f,0.f,0.f}, a1 = a0;
    float lp = 0.f;
    ushort_t* pb = &Pbuf[w][0];
    const int kq = (l15 >> 1) & 3;              // K read swizzle key

    const int nT = qt + 1;
    stage(0, 0);
    int cur = 0;
    for (int kt = 0; kt < nT; ++kt){
        __syncthreads();
        if (kt + 1 < nT) stage(kt + 1, cur ^ 1);
        const int kb0 = kt * 64;
        bf16x8 kf[4], vv0[2], vv1[2];
        #pragma unroll
        for (int ni = 0; ni < 4; ++ni)
            kf[ni] = *(const bf16x8*)&Kbuf[cur][(ni * 16 + l15) * 32 + (hi ^ kq) * 8];
        #pragma unroll
        for (int kk = 0; kk < 2; ++kk){
            int sl = kk * 4 + hi;
            vv0[kk] = *(const bf16x8*)&Vbuf[cur][l15 * 64 + (sl ^ (l15 & 7)) * 8];
            vv1[kk] = *(const bf16x8*)&Vbuf[cur][(16 + l15) * 64 + (sl ^ (l15 & 7)) * 8];
        }
        if (kt < qt)
            chain_step<false>(kf, vv0, vv1, pb, qf, kb0, qw + l15, l15, hi, a0, a1, lp);
        else
            chain_step<true >(kf, vv0, vv1, pb, qf, kb0, qw + l15, l15, hi, a0, a1, lp);
        cur ^= 1;
    }

    lp += __shfl_xor(lp, 16);
    lp += __shfl_xor(lp, 32);
    float inv = 1.0f / lp;
    ushort4 o0, o1;
    o0.x = f2bfn(a0[0]*inv); o0.y = f2bfn(a0[1]*inv);
    o0.z = f2bfn(a0[2]*inv); o0.w = f2bfn(a0[3]*inv);
    o1.x = f2bfn(a1[0]*inv); o1.y = f2bfn(a1[1]*inv);
    o1.z = f2bfn(a1[2]*inv); o1.w = f2bfn(a1[3]*inv);
    size_t base = (size_t)(qw + l15) * 1024 + h * 32;
    *(ushort4*)&yb[base + hi * 4]      = o0;
    *(ushort4*)&yb[base + 16 + hi * 4] = o1;
}

// ---------------- launcher ----------------
extern "C" void kernel_launch(void* const* d_in, const int* in_sizes, int n_in,
                              void* d_out, int out_size, void* d_ws, size_t ws_size,
                              hipStream_t stream)
{
    const float* x   = (const float*)d_in[0];
    const float* ve  = (const float*)d_in[1];
    const float* qkw = (const float*)d_in[2];
    const float* lam = (const float*)d_in[3];
    const float* cpw = (const float*)d_in[4];

    char* ws = (char*)d_ws;
    size_t o = 0;
    auto take = [&](size_t bytes) -> char* {
        char* p = ws + o; o += (bytes + 255) & ~(size_t)255; return p;
    };
    ushort_t* qb  = (ushort_t*)take((size_t)NHEADS * TSEQ * HD_ * 2);
    ushort_t* kb  = (ushort_t*)take((size_t)NHEADS * TSEQ * HD_ * 2);
    ushort_t* vtb = (ushort_t*)take((size_t)NHEADS * HD_ * TSEQ * 2);
    ushort_t* yb  = (ushort_t*)take((size_t)TSEQ * 1024 * 2);

    k_gemm_qkv<<<768, 256, 0, stream>>>(x, qkw, ve, lam, qb, kb, vtb);
    k_attn<<<1024, 256, 0, stream>>>(qb, kb, vtb, yb);
    k_gemm_out<<<512, 256, 0, stream>>>(yb, cpw, (float*)d_out);
}